// Round 5
// baseline (285.437 us; speedup 1.0000x reference)
//
#include <hip/hip_runtime.h>

typedef unsigned short ushort_t;
typedef __bf16 bf16x8 __attribute__((ext_vector_type(8)));
typedef float f32x16 __attribute__((ext_vector_type(16)));
typedef float f32x4v __attribute__((ext_vector_type(4)));
typedef unsigned int u32x4 __attribute__((ext_vector_type(4)));
typedef unsigned int u32x2 __attribute__((ext_vector_type(2)));

#define L2E 1.44269504088896340736f

__device__ __forceinline__ unsigned cvt_pk_bf16(float a, float b) {
  unsigned r;
  asm("v_cvt_pk_bf16_f32 %0, %1, %2" : "=v"(r) : "v"(a), "v"(b));
  return r;
}

__device__ __forceinline__ float fast_exp2(float v) {
#if __has_builtin(__builtin_amdgcn_exp2f)
  return __builtin_amdgcn_exp2f(v);
#else
  return exp2f(v);
#endif
}

__device__ __forceinline__ f32x16 mfma32(u32x4 a, u32x4 b, f32x16 c) {
  return __builtin_amdgcn_mfma_f32_32x32x16_bf16(
      __builtin_bit_cast(bf16x8, a), __builtin_bit_cast(bf16x8, b), c, 0, 0, 0);
}

// ---------------------------------------------------------------------------
// Projection: [320x256] W @ [256x4096] x -> Qt[b][n][32], Kt[b][m][32],
// V[b][c][m] (bf16).  grid 512 = 8 b x 64 n-tiles(64).  512 thr = 8 waves.
// LDS: only xT (64n x 256c bf16, fragment order, 32KB), staged once.
// W comes straight from L2 into A-fragments per wave (no W staging).
// ---------------------------------------------------------------------------
__global__ __launch_bounds__(512, 2) void proj_kernel(
    const float* __restrict__ x,
    const float* __restrict__ wq, const float* __restrict__ bq,
    const float* __restrict__ wk, const float* __restrict__ bk,
    const float* __restrict__ wv, const float* __restrict__ bv,
    ushort_t* __restrict__ qtg, ushort_t* __restrict__ ktg,
    ushort_t* __restrict__ vtg)
{
  __shared__ ushort_t xT[64 * 256];    // fragment-order, 32 KB

  const int tid  = threadIdx.x;
  const int b    = blockIdx.x & 7;     // batch -> XCD pin
  const int nt   = blockIdx.x >> 3;
  const int n0   = nt * 64;
  const int lane = tid & 63;
  const int wid  = tid >> 6;           // 0..7
  const int l31  = lane & 31;
  const int half = lane >> 5;

  // ---- stage xT: thread (xn = tid&63, cg = tid>>6) covers 32 channels ----
  {
    const int xn = tid & 63;
    const int cg = tid >> 6;
    const int ng = xn >> 5, l = xn & 31;
    const float* xb = x + (size_t)b * 256 * 4096 + n0 + xn;
    #pragma unroll
    for (int s = 0; s < 4; ++s) {
      const int c0 = cg * 32 + s * 8;
      float f0 = xb[(size_t)(c0+0)*4096], f1 = xb[(size_t)(c0+1)*4096];
      float f2 = xb[(size_t)(c0+2)*4096], f3 = xb[(size_t)(c0+3)*4096];
      float f4 = xb[(size_t)(c0+4)*4096], f5 = xb[(size_t)(c0+5)*4096];
      float f6 = xb[(size_t)(c0+6)*4096], f7 = xb[(size_t)(c0+7)*4096];
      u32x4 pk;
      pk.x = cvt_pk_bf16(f0, f1); pk.y = cvt_pk_bf16(f2, f3);
      pk.z = cvt_pk_bf16(f4, f5); pk.w = cvt_pk_bf16(f6, f7);
      const int c8 = c0 >> 3;                       // 0..31
      *(u32x4*)(xT + ((c8 * 2 + ng) * 32 + l) * 8) = pk;
    }
  }
  __syncthreads();

  // ---- compute: wave = (og: 160-o half) x (ng: 32-n group) x (rr) ----
  const int og = wid & 1, ng = (wid >> 1) & 1, rr = wid >> 2;
  const int n  = n0 + ng * 32 + l31;

  for (int ot = rr; ot < 5; ot += 2) {
    const int o0 = og * 160 + ot * 32;
    const int grow = o0 + l31;
    const float* wrow = (o0 < 32) ? (wq + grow * 256)
                      : (o0 < 64) ? (wk + (grow - 32) * 256)
                                  : (wv + (grow - 64) * 256);
    f32x16 acc = {};
    #pragma unroll
    for (int kc = 0; kc < 16; ++kc) {
      f32x4v g0 = *(const f32x4v*)(wrow + kc * 16 + half * 8);
      f32x4v g1 = *(const f32x4v*)(wrow + kc * 16 + half * 8 + 4);
      u32x4 af;
      af.x = cvt_pk_bf16(g0.x, g0.y); af.y = cvt_pk_bf16(g0.z, g0.w);
      af.z = cvt_pk_bf16(g1.x, g1.y); af.w = cvt_pk_bf16(g1.z, g1.w);
      u32x4 bf = *(const u32x4*)(xT + ((kc * 2 + half) * 2 + ng) * 256 + l31 * 8);
      acc = mfma32(af, bf, acc);
    }
    if (o0 < 64) {
      // o0==0 -> Q, o0==32 -> K ; store [n][o] bf16
      ushort_t* dst = (o0 == 0) ? qtg : ktg;
      const float* bias = (o0 == 0) ? bq : bk;
      const size_t rowbase = ((size_t)b * 4096 + n) * 32;
      #pragma unroll
      for (int g = 0; g < 4; ++g) {
        const int ob = 8 * g + 4 * half;          // D row = (r&3)+8*(r>>2)+4*half
        float v0 = acc[4*g+0] + bias[ob+0];
        float v1 = acc[4*g+1] + bias[ob+1];
        float v2 = acc[4*g+2] + bias[ob+2];
        float v3 = acc[4*g+3] + bias[ob+3];
        u32x2 pk2; pk2.x = cvt_pk_bf16(v0, v1); pk2.y = cvt_pk_bf16(v2, v3);
        *(u32x2*)(dst + rowbase + ob) = pk2;
      }
    } else {
      const int cbase = o0 - 64;
      #pragma unroll
      for (int r = 0; r < 16; ++r) {
        const int c = cbase + (r & 3) + 8 * (r >> 2) + 4 * half;
        float v = acc[r] + bv[c];
        vtg[((size_t)b * 256 + c) * 4096 + n] = (ushort_t)cvt_pk_bf16(v, v);
      }
    }
  }
}

// online-softmax + P-pack for one 32q S-tile (proven round-1 construction)
#define SOFTMAX_PACK(S, MR, LR, OB, PB0, PB1) do {                            \
  float y0 = fmaxf(fmaxf(S[0],  S[1]),  fmaxf(S[2],  S[3]));                  \
  float y1 = fmaxf(fmaxf(S[4],  S[5]),  fmaxf(S[6],  S[7]));                  \
  float y2 = fmaxf(fmaxf(S[8],  S[9]),  fmaxf(S[10], S[11]));                 \
  float y3 = fmaxf(fmaxf(S[12], S[13]), fmaxf(S[14], S[15]));                 \
  const float vmx  = fmaxf(fmaxf(y0, y1), fmaxf(y2, y3));                     \
  const float pmax = fmaxf(vmx, __shfl_xor(vmx, 32, 64));                     \
  if (__any(pmax > (MR) + 8.0f)) {                                            \
    const float mnew = fmaxf((MR), pmax);                                     \
    const float sc   = fast_exp2(((MR) - mnew) * L2E);                        \
    (LR) *= sc;                                                               \
    _Pragma("unroll")                                                         \
    for (int ct_ = 0; ct_ < 4; ++ct_) {                                       \
      _Pragma("unroll")                                                       \
      for (int r_ = 0; r_ < 16; ++r_) oacc[(OB) + ct_][r_] *= sc;             \
    }                                                                         \
    (MR) = mnew;                                                              \
  }                                                                           \
  const float ml2 = (MR) * L2E;                                               \
  float p_[16];                                                               \
  _Pragma("unroll")                                                           \
  for (int r_ = 0; r_ < 16; ++r_) p_[r_] = fast_exp2(fmaf(S[r_], L2E, -ml2)); \
  const float ps = (((p_[0]+p_[1])+(p_[2]+p_[3])) + ((p_[4]+p_[5])+(p_[6]+p_[7]))) \
                 + (((p_[8]+p_[9])+(p_[10]+p_[11])) + ((p_[12]+p_[13])+(p_[14]+p_[15]))); \
  (LR) += ps + __shfl_xor(ps, 32, 64);                                        \
  const unsigned wd0 = cvt_pk_bf16(p_[0],  p_[1]),  wd1 = cvt_pk_bf16(p_[2],  p_[3]);  \
  const unsigned wd2 = cvt_pk_bf16(p_[4],  p_[5]),  wd3 = cvt_pk_bf16(p_[6],  p_[7]);  \
  const unsigned wd4 = cvt_pk_bf16(p_[8],  p_[9]),  wd5 = cvt_pk_bf16(p_[10], p_[11]); \
  const unsigned wd6 = cvt_pk_bf16(p_[12], p_[13]), wd7 = cvt_pk_bf16(p_[14], p_[15]); \
  const unsigned pw0 = __shfl_xor((int)wd0, 32, 64), pw1 = __shfl_xor((int)wd1, 32, 64); \
  const unsigned pw2 = __shfl_xor((int)wd2, 32, 64), pw3 = __shfl_xor((int)wd3, 32, 64); \
  const unsigned pw4 = __shfl_xor((int)wd4, 32, 64), pw5 = __shfl_xor((int)wd5, 32, 64); \
  const unsigned pw6 = __shfl_xor((int)wd6, 32, 64), pw7 = __shfl_xor((int)wd7, 32, 64); \
  PB0.x = half ? pw2 : wd0;  PB0.y = half ? pw3 : wd1;                        \
  PB0.z = half ? wd2 : pw0;  PB0.w = half ? wd3 : pw1;                        \
  PB1.x = half ? pw6 : wd4;  PB1.y = half ? pw7 : wd5;                        \
  PB1.z = half ? wd6 : pw4;  PB1.w = half ? wd7 : pw5;                        \
} while (0)

// ---------------------------------------------------------------------------
// Flash attention, barrier-free main loop.  grid 512 = 8 b x 64 q-tiles(64q);
// 256 thr = 4 waves = 2 cs(128ch) x 2 ks(tile parity).  Wave: 64 q x 128 ch,
// 64 tiles, K and V fragments gathered straight from L2 into registers —
// no LDS, no __syncthreads, no manual waitcnt in the loop.  ks pairs merge
// (m,l,O) once through LDS at the end.
// ---------------------------------------------------------------------------
__global__ __launch_bounds__(256, 2) void attn_kernel(
    const ushort_t* __restrict__ qtg, const ushort_t* __restrict__ ktg,
    const ushort_t* __restrict__ vtg, const float* __restrict__ x,
    const float* __restrict__ gamma, float* __restrict__ out)
{
  __shared__ float obuf[16][16][64];   // [slot][r][lane] 64 KB (merge only)
  __shared__ float mls[2][8][64];      // m / l exchange, 4 KB

  const int tid  = threadIdx.x;
  const int lane = tid & 63;
  const int wid  = tid >> 6;           // 0..3
  const int l31  = lane & 31;
  const int half = lane >> 5;
  const int ks   = wid & 1;            // tile parity
  const int cs   = wid >> 1;           // channel half
  const int b    = blockIdx.x & 7;     // batch -> XCD pin (V L2-resident)
  const int qt   = blockIdx.x >> 3;    // 0..63
  const int qbase = qt * 64;

  const ushort_t* ktb = ktg + (size_t)b * 4096 * 32;
  const ushort_t* vr  = vtg + ((size_t)b * 256 + cs * 128 + l31) * 4096;

  // persistent Q B-fragments (2 q-subtiles x 2 o-chunks)
  const ushort_t* qr0 = qtg + ((size_t)b * 4096 + qbase + l31) * 32;
  const ushort_t* qr1 = qr0 + 32 * 32;
  const u32x4 qf00 = *(const u32x4*)(qr0 + half * 8);
  const u32x4 qf01 = *(const u32x4*)(qr0 + 16 + half * 8);
  const u32x4 qf10 = *(const u32x4*)(qr1 + half * 8);
  const u32x4 qf11 = *(const u32x4*)(qr1 + 16 + half * 8);

  // K fragments for first tile (t = ks), straight from global
  u32x4 kf0 = *(const u32x4*)(ktb + (size_t)(ks * 32 + l31) * 32 + half * 8);
  u32x4 kf1 = *(const u32x4*)(ktb + (size_t)(ks * 32 + l31) * 32 + 16 + half * 8);
  u32x4 kn0 = kf0, kn1 = kf1;

  float mr0 = -3.0e38f, mr1 = -3.0e38f, lr0 = 0.0f, lr1 = 0.0f;
  f32x16 oacc[8] = {};                 // [qt2*4 + ct]

  for (int i = 0; i < 64; ++i) {
    const int t = 2 * i + ks;

    // V fragments for tile t: 16B/lane register gathers (used at PV)
    u32x4 vf[4][2];
    #pragma unroll
    for (int ct = 0; ct < 4; ++ct)
      #pragma unroll
      for (int mh = 0; mh < 2; ++mh)
        vf[ct][mh] = *(const u32x4*)(vr + (size_t)ct * 32 * 4096 +
                                     t * 32 + mh * 16 + half * 8);

    // S^T = K . Q^T for both q-subtiles
    f32x16 s0 = {}, s1 = {};
    __builtin_amdgcn_s_setprio(1);
    s0 = mfma32(kf0, qf00, s0);  s0 = mfma32(kf1, qf01, s0);
    s1 = mfma32(kf0, qf10, s1);  s1 = mfma32(kf1, qf11, s1);
    __builtin_amdgcn_s_setprio(0);

    // K prefetch for tile t+2
    if (i < 63) {
      const ushort_t* kr = ktb + (size_t)((t + 2) * 32 + l31) * 32;
      kn0 = *(const u32x4*)(kr + half * 8);
      kn1 = *(const u32x4*)(kr + 16 + half * 8);
    }

    // qt2 = 0: softmax + PV
    {
      u32x4 pb0, pb1;
      SOFTMAX_PACK(s0, mr0, lr0, 0, pb0, pb1);
      __builtin_amdgcn_s_setprio(1);
      #pragma unroll
      for (int ct = 0; ct < 4; ++ct) {
        oacc[ct] = mfma32(vf[ct][0], pb0, oacc[ct]);
        oacc[ct] = mfma32(vf[ct][1], pb1, oacc[ct]);
      }
      __builtin_amdgcn_s_setprio(0);
    }
    // qt2 = 1: softmax + PV
    {
      u32x4 pb0, pb1;
      SOFTMAX_PACK(s1, mr1, lr1, 4, pb0, pb1);
      __builtin_amdgcn_s_setprio(1);
      #pragma unroll
      for (int ct = 0; ct < 4; ++ct) {
        oacc[4 + ct] = mfma32(vf[ct][0], pb0, oacc[4 + ct]);
        oacc[4 + ct] = mfma32(vf[ct][1], pb1, oacc[4 + ct]);
      }
      __builtin_amdgcn_s_setprio(0);
    }

    kf0 = kn0; kf1 = kn1;
  }

  // ---- flash merge across ks pairs (partner wave = wid ^ 1) ----
  mls[0][wid * 2 + 0][lane] = mr0;  mls[0][wid * 2 + 1][lane] = mr1;
  mls[1][wid * 2 + 0][lane] = lr0;  mls[1][wid * 2 + 1][lane] = lr1;
  __syncthreads();
  const int pw = (wid ^ 1) * 2;
  const float mO0 = mls[0][pw + 0][lane], lO0 = mls[1][pw + 0][lane];
  const float mO1 = mls[0][pw + 1][lane], lO1 = mls[1][pw + 1][lane];
  const float mS0 = fmaxf(mr0, mO0), mS1 = fmaxf(mr1, mO1);
  const float aS0 = fast_exp2((mr0 - mS0) * L2E), aO0 = fast_exp2((mO0 - mS0) * L2E);
  const float aS1 = fast_exp2((mr1 - mS1) * L2E), aO1 = fast_exp2((mO1 - mS1) * L2E);
  const float li0 = 1.0f / (aS0 * lr0 + aO0 * lO0);
  const float li1 = 1.0f / (aS1 * lr1 + aO1 * lO1);

  if (ks == 1) {                       // partner writes scaled O
    #pragma unroll
    for (int qt2 = 0; qt2 < 2; ++qt2) {
      const float aS = qt2 ? aS1 : aS0;
      #pragma unroll
      for (int ct = 0; ct < 4; ++ct) {
        const int slot = cs * 8 + qt2 * 4 + ct;
        #pragma unroll
        for (int r = 0; r < 16; ++r)
          obuf[slot][r][lane] = aS * oacc[qt2 * 4 + ct][r];
      }
    }
  }
  __syncthreads();
  if (ks == 0) {                       // combine + store
    const float g = gamma[0];
    const size_t base = (size_t)b * 256 * 4096;
    #pragma unroll
    for (int qt2 = 0; qt2 < 2; ++qt2) {
      const float aS = qt2 ? aS1 : aS0;
      const float li = qt2 ? li1 : li0;
      const size_t n = qbase + qt2 * 32 + l31;
      #pragma unroll
      for (int ct = 0; ct < 4; ++ct) {
        const int slot = cs * 8 + qt2 * 4 + ct;
        #pragma unroll
        for (int r = 0; r < 16; ++r) {
          const float oS = aS * oacc[qt2 * 4 + ct][r] + obuf[slot][r][lane];
          const int c = cs * 128 + ct * 32 + (r & 3) + 8 * (r >> 2) + 4 * half;
          const size_t off = base + (size_t)c * 4096 + n;
          out[off] = x[off] + g * (oS * li);
        }
      }
    }
  }
}

extern "C" void kernel_launch(void* const* d_in, const int* in_sizes, int n_in,
                              void* d_out, int out_size, void* d_ws, size_t ws_size,
                              hipStream_t stream) {
  (void)in_sizes; (void)n_in; (void)out_size; (void)ws_size;
  const float* x     = (const float*)d_in[0];
  const float* wq    = (const float*)d_in[1];
  const float* bq    = (const float*)d_in[2];
  const float* wk    = (const float*)d_in[3];
  const float* bk    = (const float*)d_in[4];
  const float* wv    = (const float*)d_in[5];
  const float* bv    = (const float*)d_in[6];
  const float* gamma = (const float*)d_in[7];
  float* out = (float*)d_out;

  ushort_t* ws  = (ushort_t*)d_ws;
  ushort_t* qtw = ws;                              // [8][4096][32] bf16
  ushort_t* ktw = ws + (size_t)8*4096*32;          // [8][4096][32] bf16
  ushort_t* vww = ws + (size_t)2*8*4096*32;        // [8][256][4096] bf16

  proj_kernel<<<512, 512, 0, stream>>>(x, wq, bq, wk, bk, wv, bv, qtw, ktw, vww);
  attn_kernel<<<512, 256, 0, stream>>>(qtw, ktw, vww, x, gamma, out);
}

// Round 6
// 269.519 us; speedup vs baseline: 1.0591x; 1.0591x over previous
//
#include <hip/hip_runtime.h>

typedef unsigned short ushort_t;
typedef __bf16 bf16x8 __attribute__((ext_vector_type(8)));
typedef float f32x16 __attribute__((ext_vector_type(16)));
typedef float f32x4v __attribute__((ext_vector_type(4)));
typedef unsigned int u32x4 __attribute__((ext_vector_type(4)));
typedef unsigned int u32x2 __attribute__((ext_vector_type(2)));

#define L2E 1.44269504088896340736f

__device__ __forceinline__ unsigned cvt_pk_bf16(float a, float b) {
  unsigned r;
  asm("v_cvt_pk_bf16_f32 %0, %1, %2" : "=v"(r) : "v"(a), "v"(b));
  return r;
}

__device__ __forceinline__ float fast_exp2(float v) {
#if __has_builtin(__builtin_amdgcn_exp2f)
  return __builtin_amdgcn_exp2f(v);
#else
  return exp2f(v);
#endif
}

__device__ __forceinline__ f32x16 mfma32(u32x4 a, u32x4 b, f32x16 c) {
  return __builtin_amdgcn_mfma_f32_32x32x16_bf16(
      __builtin_bit_cast(bf16x8, a), __builtin_bit_cast(bf16x8, b), c, 0, 0, 0);
}

// ---------------------------------------------------------------------------
// Projection: [320x256] W @ [256x4096] x -> Qt[b][n][32], Kt[b][m][32],
// V[b][c][m] (bf16).  grid 512 = 8 b x 64 n-tiles(64).  512 thr = 8 waves.
// LDS 73728B (proven size): xT 32KB fragment-order + wl 40KB (160 W-rows x
// 128 c, XOR-swizzled words).  4 phases = (o-half x c-half); acc carried
// across c-phases.  All W reads coalesced; all LDS frag reads lane-linear.
// ---------------------------------------------------------------------------
__global__ __launch_bounds__(512, 2) void proj_kernel(
    const float* __restrict__ x,
    const float* __restrict__ wq, const float* __restrict__ bq,
    const float* __restrict__ wk, const float* __restrict__ bk,
    const float* __restrict__ wv, const float* __restrict__ bv,
    ushort_t* __restrict__ qtg, ushort_t* __restrict__ ktg,
    ushort_t* __restrict__ vtg)
{
  __shared__ ushort_t xT[64 * 256];          // 32 KB
  __shared__ ushort_t wl[160 * 128];         // 40 KB

  const int tid  = threadIdx.x;
  const int b    = blockIdx.x & 7;     // batch -> XCD pin
  const int nt   = blockIdx.x >> 3;
  const int n0   = nt * 64;
  const int lane = tid & 63;
  const int wid  = tid >> 6;           // 0..7
  const int l31  = lane & 31;
  const int half = lane >> 5;

  // ---- stage xT (fragment order, proven r5 formula) ----
  {
    const int xn = tid & 63;
    const int cg = tid >> 6;
    const int ng = xn >> 5, l = xn & 31;
    const float* xb = x + (size_t)b * 256 * 4096 + n0 + xn;
    #pragma unroll
    for (int s = 0; s < 4; ++s) {
      const int c0 = cg * 32 + s * 8;
      float f0 = xb[(size_t)(c0+0)*4096], f1 = xb[(size_t)(c0+1)*4096];
      float f2 = xb[(size_t)(c0+2)*4096], f3 = xb[(size_t)(c0+3)*4096];
      float f4 = xb[(size_t)(c0+4)*4096], f5 = xb[(size_t)(c0+5)*4096];
      float f6 = xb[(size_t)(c0+6)*4096], f7 = xb[(size_t)(c0+7)*4096];
      u32x4 pk;
      pk.x = cvt_pk_bf16(f0, f1); pk.y = cvt_pk_bf16(f2, f3);
      pk.z = cvt_pk_bf16(f4, f5); pk.w = cvt_pk_bf16(f6, f7);
      const int c8 = c0 >> 3;
      *(u32x4*)((char*)xT + (c8 * 2 + ng) * 512 + l * 16) = pk;
    }
  }

  for (int h = 0; h < 2; ++h) {
    f32x16 acc[2] = {};
    #pragma unroll
    for (int cc = 0; cc < 2; ++cc) {
      __syncthreads();   // prior wl reads done (covers xT stage on first)
      // ---- stage W chunk: rows [h*160,+160), cols [cc*128,+128) ----
      #pragma unroll
      for (int j = 0; j < 5; ++j) {
        const int lin   = j * 512 + tid;
        const int c8l   = lin & 15;          // local 8-ch chunk
        const int row_l = lin >> 4;          // 0..159
        const int grow  = h * 160 + row_l;
        const float* wrow = (grow < 32) ? (wq + grow * 256)
                          : (grow < 64) ? (wk + (grow - 32) * 256)
                                        : (wv + (grow - 64) * 256);
        f32x4v g0 = *(const f32x4v*)(wrow + (cc * 16 + c8l) * 8);
        f32x4v g1 = *(const f32x4v*)(wrow + (cc * 16 + c8l) * 8 + 4);
        u32x4 pk;
        pk.x = cvt_pk_bf16(g0.x, g0.y); pk.y = cvt_pk_bf16(g0.z, g0.w);
        pk.z = cvt_pk_bf16(g1.x, g1.y); pk.w = cvt_pk_bf16(g1.z, g1.w);
        const int addr = ((((row_l >> 5) * 8 + (c8l >> 1)) * 2 + (c8l & 1)) * 512
                          + (row_l & 31) * 16) ^ ((c8l & 7) << 4);
        *(u32x4*)((char*)wl + addr) = pk;
      }
      __syncthreads();
      // ---- accumulate kc 0..7 of this c-phase for this wave's tiles ----
      #pragma unroll
      for (int tt = 0; tt < 2; ++tt) {
        const int t = wid + tt * 8;
        if (t < 10) {
          const int ot = t >> 1, ng = t & 1;
          #pragma unroll
          for (int kc = 0; kc < 8; ++kc) {
            const int aaddr = ((((ot * 8 + kc) * 2 + half) * 512) + l31 * 16)
                              ^ (((kc * 2 + half) & 7) << 4);
            u32x4 af = *(const u32x4*)((const char*)wl + aaddr);
            const int c8g = cc * 16 + kc * 2 + half;
            u32x4 bf = *(const u32x4*)((const char*)xT + (c8g * 2 + ng) * 512 + l31 * 16);
            acc[tt] = mfma32(af, bf, acc[tt]);
          }
        }
      }
    }
    // ---- store this o-half's tiles ----
    #pragma unroll
    for (int tt = 0; tt < 2; ++tt) {
      const int t = wid + tt * 8;
      if (t < 10) {
        const int ot = t >> 1, ng = t & 1;
        const int o0 = h * 160 + ot * 32;
        const int n  = n0 + ng * 32 + l31;
        if (o0 < 64) {
          ushort_t* dst = (o0 == 0) ? qtg : ktg;
          const float* bias = (o0 == 0) ? bq : bk;
          const size_t rowbase = ((size_t)b * 4096 + n) * 32;
          #pragma unroll
          for (int g = 0; g < 4; ++g) {
            const int ob = 8 * g + 4 * half;
            float v0 = acc[tt][4*g+0] + bias[ob+0];
            float v1 = acc[tt][4*g+1] + bias[ob+1];
            float v2 = acc[tt][4*g+2] + bias[ob+2];
            float v3 = acc[tt][4*g+3] + bias[ob+3];
            u32x2 pk2; pk2.x = cvt_pk_bf16(v0, v1); pk2.y = cvt_pk_bf16(v2, v3);
            *(u32x2*)(dst + rowbase + ob) = pk2;
          }
        } else {
          const int cbase = o0 - 64;
          #pragma unroll
          for (int r = 0; r < 16; ++r) {
            const int c = cbase + (r & 3) + 8 * (r >> 2) + 4 * half;
            float v = acc[tt][r] + bv[c];
            vtg[((size_t)b * 256 + c) * 4096 + n] = (ushort_t)cvt_pk_bf16(v, v);
          }
        }
      }
    }
  }
}

// online-softmax + P-pack for one 32q S-tile (proven round-1 construction)
#define SOFTMAX_PACK(S, MR, LR, OB, PB0, PB1) do {                            \
  float y0 = fmaxf(fmaxf(S[0],  S[1]),  fmaxf(S[2],  S[3]));                  \
  float y1 = fmaxf(fmaxf(S[4],  S[5]),  fmaxf(S[6],  S[7]));                  \
  float y2 = fmaxf(fmaxf(S[8],  S[9]),  fmaxf(S[10], S[11]));                 \
  float y3 = fmaxf(fmaxf(S[12], S[13]), fmaxf(S[14], S[15]));                 \
  const float vmx  = fmaxf(fmaxf(y0, y1), fmaxf(y2, y3));                     \
  const float pmax = fmaxf(vmx, __shfl_xor(vmx, 32, 64));                     \
  if (__any(pmax > (MR) + 8.0f)) {                                            \
    const float mnew = fmaxf((MR), pmax);                                     \
    const float sc   = fast_exp2(((MR) - mnew) * L2E);                        \
    (LR) *= sc;                                                               \
    _Pragma("unroll")                                                         \
    for (int ct_ = 0; ct_ < 4; ++ct_) {                                       \
      _Pragma("unroll")                                                       \
      for (int r_ = 0; r_ < 16; ++r_) oacc[(OB) + ct_][r_] *= sc;             \
    }                                                                         \
    (MR) = mnew;                                                              \
  }                                                                           \
  const float ml2 = (MR) * L2E;                                               \
  float p_[16];                                                               \
  _Pragma("unroll")                                                           \
  for (int r_ = 0; r_ < 16; ++r_) p_[r_] = fast_exp2(fmaf(S[r_], L2E, -ml2)); \
  const float ps = (((p_[0]+p_[1])+(p_[2]+p_[3])) + ((p_[4]+p_[5])+(p_[6]+p_[7]))) \
                 + (((p_[8]+p_[9])+(p_[10]+p_[11])) + ((p_[12]+p_[13])+(p_[14]+p_[15]))); \
  (LR) += ps + __shfl_xor(ps, 32, 64);                                        \
  const unsigned wd0 = cvt_pk_bf16(p_[0],  p_[1]),  wd1 = cvt_pk_bf16(p_[2],  p_[3]);  \
  const unsigned wd2 = cvt_pk_bf16(p_[4],  p_[5]),  wd3 = cvt_pk_bf16(p_[6],  p_[7]);  \
  const unsigned wd4 = cvt_pk_bf16(p_[8],  p_[9]),  wd5 = cvt_pk_bf16(p_[10], p_[11]); \
  const unsigned wd6 = cvt_pk_bf16(p_[12], p_[13]), wd7 = cvt_pk_bf16(p_[14], p_[15]); \
  const unsigned pw0 = __shfl_xor((int)wd0, 32, 64), pw1 = __shfl_xor((int)wd1, 32, 64); \
  const unsigned pw2 = __shfl_xor((int)wd2, 32, 64), pw3 = __shfl_xor((int)wd3, 32, 64); \
  const unsigned pw4 = __shfl_xor((int)wd4, 32, 64), pw5 = __shfl_xor((int)wd5, 32, 64); \
  const unsigned pw6 = __shfl_xor((int)wd6, 32, 64), pw7 = __shfl_xor((int)wd7, 32, 64); \
  PB0.x = half ? pw2 : wd0;  PB0.y = half ? pw3 : wd1;                        \
  PB0.z = half ? wd2 : pw0;  PB0.w = half ? wd3 : pw1;                        \
  PB1.x = half ? pw6 : wd4;  PB1.y = half ? pw7 : wd5;                        \
  PB1.z = half ? wd6 : pw4;  PB1.w = half ? wd7 : pw5;                        \
} while (0)

// ---------------------------------------------------------------------------
// Flash attention, barrier-free loop + private per-wave LDS V double-buffer.
// grid 512 = 8 b x 64 q-tiles(64q); 256 thr = 4 waves = 2 cs(128ch) x 2 ks.
// Per iter per wave: 2 K reg-loads + 8 global_load_lds (next tile) ->
// s_waitcnt vmcnt(10) -> 8 lane-linear ds_read_b128 -> QK/softmax/PV.
// No __syncthreads in the loop.  ks pairs flash-merge at the end (obuf
// aliases the V buffers).
// ---------------------------------------------------------------------------
__global__ __launch_bounds__(256, 2) void attn_kernel(
    const ushort_t* __restrict__ qtg, const ushort_t* __restrict__ ktg,
    const ushort_t* __restrict__ vtg, const float* __restrict__ x,
    const float* __restrict__ gamma, float* __restrict__ out)
{
  __shared__ __align__(16) char smem[69632];  // [0,64K): 4x16KB wave V dbufs
                                              //          (aliased by merge obuf)
                                              // [64K,68K): m/l exchange

  const int tid  = threadIdx.x;
  const int lane = tid & 63;
  const int wid  = tid >> 6;           // 0..3
  const int l31  = lane & 31;
  const int half = lane >> 5;
  const int ks   = wid & 1;            // tile parity
  const int cs   = wid >> 1;           // channel half
  const int b    = blockIdx.x & 7;     // batch -> XCD pin (V L2-resident)
  const int qt   = blockIdx.x >> 3;    // 0..63
  const int qbase = qt * 64;

  const ushort_t* ktb = ktg + (size_t)b * 4096 * 32;
  const ushort_t* vgb = vtg + (size_t)b * 256 * 4096;
  char* vbuf = smem + wid * 16384;     // private: 2 x 8KB

  // persistent Q B-fragments (2 q-subtiles x 2 o-chunks)
  const ushort_t* qr0 = qtg + ((size_t)b * 4096 + qbase + l31) * 32;
  const ushort_t* qr1 = qr0 + 32 * 32;
  const u32x4 qf00 = *(const u32x4*)(qr0 + half * 8);
  const u32x4 qf01 = *(const u32x4*)(qr0 + 16 + half * 8);
  const u32x4 qf10 = *(const u32x4*)(qr1 + half * 8);
  const u32x4 qf11 = *(const u32x4*)(qr1 + 16 + half * 8);

  // stage V tile t into private buffer db (8 x 1KB, r4-proven addressing)
  #define STAGE_V(db, t_) do {                                                \
    _Pragma("unroll")                                                         \
    for (int j = 0; j < 8; ++j) {                                             \
      const ushort_t* gp = vgb + (size_t)(cs*128 + (j>>1)*32 + l31)*4096      \
                               + (t_)*32 + ((j&1)*2 + half)*8;                \
      const char* lp = vbuf + (db)*8192 + j*1024;                             \
      __builtin_amdgcn_global_load_lds(                                       \
          (const __attribute__((address_space(1))) void*)gp,                  \
          (__attribute__((address_space(3))) void*)lp, 16, 0, 0);             \
    }                                                                         \
  } while (0)

  // prologue: K(t0) regs + V(t0) -> buf0
  u32x4 kf0 = *(const u32x4*)(ktb + (size_t)(ks * 32 + l31) * 32 + half * 8);
  u32x4 kf1 = *(const u32x4*)(ktb + (size_t)(ks * 32 + l31) * 32 + 16 + half * 8);
  STAGE_V(0, ks);

  float mr0 = -3.0e38f, mr1 = -3.0e38f, lr0 = 0.0f, lr1 = 0.0f;
  f32x16 oacc[8] = {};                 // [qt2*4 + ct]

  for (int i = 0; i < 64; ++i) {
    const int t  = 2 * i + ks;
    const int tn = (i < 63) ? (t + 2) : t;   // clamped -> uniform 10 issues

    // K prefetch (2 vmem), then V stage for next tile (8 vmem)
    const ushort_t* kr = ktb + (size_t)(tn * 32 + l31) * 32;
    u32x4 kn0 = *(const u32x4*)(kr + half * 8);
    u32x4 kn1 = *(const u32x4*)(kr + 16 + half * 8);
    STAGE_V((i + 1) & 1, tn);

    // wait: everything older than this iter's 10 issues (V(t), K(t) done)
    asm volatile("s_waitcnt vmcnt(10)" ::: "memory");
    __builtin_amdgcn_sched_barrier(0);

    // V fragments: lane-linear conflict-free ds_read_b128
    const char* vb = vbuf + (i & 1) * 8192;
    u32x4 vf[4][2];
    #pragma unroll
    for (int ct = 0; ct < 4; ++ct)
      #pragma unroll
      for (int mh = 0; mh < 2; ++mh)
        vf[ct][mh] = *(const u32x4*)(vb + (ct*4 + mh*2 + half) * 512 + l31 * 16);

    // S^T = K . Q^T for both q-subtiles
    f32x16 s0 = {}, s1 = {};
    __builtin_amdgcn_s_setprio(1);
    s0 = mfma32(kf0, qf00, s0);  s0 = mfma32(kf1, qf01, s0);
    s1 = mfma32(kf0, qf10, s1);  s1 = mfma32(kf1, qf11, s1);
    __builtin_amdgcn_s_setprio(0);

    // qt2 = 0
    {
      u32x4 pb0, pb1;
      SOFTMAX_PACK(s0, mr0, lr0, 0, pb0, pb1);
      __builtin_amdgcn_s_setprio(1);
      #pragma unroll
      for (int ct = 0; ct < 4; ++ct) {
        oacc[ct] = mfma32(vf[ct][0], pb0, oacc[ct]);
        oacc[ct] = mfma32(vf[ct][1], pb1, oacc[ct]);
      }
      __builtin_amdgcn_s_setprio(0);
    }
    // qt2 = 1
    {
      u32x4 pb0, pb1;
      SOFTMAX_PACK(s1, mr1, lr1, 4, pb0, pb1);
      __builtin_amdgcn_s_setprio(1);
      #pragma unroll
      for (int ct = 0; ct < 4; ++ct) {
        oacc[4 + ct] = mfma32(vf[ct][0], pb0, oacc[4 + ct]);
        oacc[4 + ct] = mfma32(vf[ct][1], pb1, oacc[4 + ct]);
      }
      __builtin_amdgcn_s_setprio(0);
    }

    kf0 = kn0; kf1 = kn1;
  }

  // drain the final (redundant) stage before aliasing the buffers
  asm volatile("s_waitcnt vmcnt(0)" ::: "memory");

  // ---- flash merge across ks pairs (partner wave = wid ^ 1) ----
  float* mls = (float*)(smem + 65536);       // [2][8][64]
  mls[(0*8 + wid*2 + 0)*64 + lane] = mr0;
  mls[(0*8 + wid*2 + 1)*64 + lane] = mr1;
  mls[(1*8 + wid*2 + 0)*64 + lane] = lr0;
  mls[(1*8 + wid*2 + 1)*64 + lane] = lr1;
  __syncthreads();
  const int pw = (wid ^ 1) * 2;
  const float mO0 = mls[(0*8 + pw + 0)*64 + lane], lO0 = mls[(1*8 + pw + 0)*64 + lane];
  const float mO1 = mls[(0*8 + pw + 1)*64 + lane], lO1 = mls[(1*8 + pw + 1)*64 + lane];
  const float mS0 = fmaxf(mr0, mO0), mS1 = fmaxf(mr1, mO1);
  const float aS0 = fast_exp2((mr0 - mS0) * L2E), aO0 = fast_exp2((mO0 - mS0) * L2E);
  const float aS1 = fast_exp2((mr1 - mS1) * L2E), aO1 = fast_exp2((mO1 - mS1) * L2E);
  const float li0 = 1.0f / (aS0 * lr0 + aO0 * lO0);
  const float li1 = 1.0f / (aS1 * lr1 + aO1 * lO1);

  float (*obuf)[16][64] = (float (*)[16][64])smem;   // 16 slots, aliases vbufs

  if (ks == 1) {                       // partner writes scaled O
    #pragma unroll
    for (int qt2 = 0; qt2 < 2; ++qt2) {
      const float aS = qt2 ? aS1 : aS0;
      #pragma unroll
      for (int ct = 0; ct < 4; ++ct) {
        const int slot = cs * 8 + qt2 * 4 + ct;
        #pragma unroll
        for (int r = 0; r < 16; ++r)
          obuf[slot][r][lane] = aS * oacc[qt2 * 4 + ct][r];
      }
    }
  }
  __syncthreads();
  if (ks == 0) {                       // combine + store
    const float g = gamma[0];
    const size_t base = (size_t)b * 256 * 4096;
    #pragma unroll
    for (int qt2 = 0; qt2 < 2; ++qt2) {
      const float aS = qt2 ? aS1 : aS0;
      const float li = qt2 ? li1 : li0;
      const size_t n = qbase + qt2 * 32 + l31;
      #pragma unroll
      for (int ct = 0; ct < 4; ++ct) {
        const int slot = cs * 8 + qt2 * 4 + ct;
        #pragma unroll
        for (int r = 0; r < 16; ++r) {
          const float oS = aS * oacc[qt2 * 4 + ct][r] + obuf[slot][r][lane];
          const int c = cs * 128 + ct * 32 + (r & 3) + 8 * (r >> 2) + 4 * half;
          const size_t off = base + (size_t)c * 4096 + n;
          out[off] = x[off] + g * (oS * li);
        }
      }
    }
  }
}

extern "C" void kernel_launch(void* const* d_in, const int* in_sizes, int n_in,
                              void* d_out, int out_size, void* d_ws, size_t ws_size,
                              hipStream_t stream) {
  (void)in_sizes; (void)n_in; (void)out_size; (void)ws_size;
  const float* x     = (const float*)d_in[0];
  const float* wq    = (const float*)d_in[1];
  const float* bq    = (const float*)d_in[2];
  const float* wk    = (const float*)d_in[3];
  const float* bk    = (const float*)d_in[4];
  const float* wv    = (const float*)d_in[5];
  const float* bv    = (const float*)d_in[6];
  const float* gamma = (const float*)d_in[7];
  float* out = (float*)d_out;

  ushort_t* ws  = (ushort_t*)d_ws;
  ushort_t* qtw = ws;                              // [8][4096][32] bf16
  ushort_t* ktw = ws + (size_t)8*4096*32;          // [8][4096][32] bf16
  ushort_t* vww = ws + (size_t)2*8*4096*32;        // [8][256][4096] bf16

  proj_kernel<<<512, 512, 0, stream>>>(x, wq, bq, wk, bk, wv, bv, qtw, ktw, vww);
  attn_kernel<<<512, 256, 0, stream>>>(qtw, ktw, vww, x, gamma, out);
}

// Round 7
// 260.656 us; speedup vs baseline: 1.0951x; 1.0340x over previous
//
#include <hip/hip_runtime.h>

typedef unsigned short ushort_t;
typedef __bf16 bf16x8 __attribute__((ext_vector_type(8)));
typedef float f32x16 __attribute__((ext_vector_type(16)));
typedef float f32x4v __attribute__((ext_vector_type(4)));
typedef unsigned int u32x4 __attribute__((ext_vector_type(4)));
typedef unsigned int u32x2 __attribute__((ext_vector_type(2)));

#define L2E 1.44269504088896340736f

__device__ __forceinline__ unsigned cvt_pk_bf16(float a, float b) {
  unsigned r;
  asm("v_cvt_pk_bf16_f32 %0, %1, %2" : "=v"(r) : "v"(a), "v"(b));
  return r;
}

__device__ __forceinline__ float fast_exp2(float v) {
#if __has_builtin(__builtin_amdgcn_exp2f)
  return __builtin_amdgcn_exp2f(v);
#else
  return exp2f(v);
#endif
}

__device__ __forceinline__ f32x16 mfma32(u32x4 a, u32x4 b, f32x16 c) {
  return __builtin_amdgcn_mfma_f32_32x32x16_bf16(
      __builtin_bit_cast(bf16x8, a), __builtin_bit_cast(bf16x8, b), c, 0, 0, 0);
}

// ---------------------------------------------------------------------------
// ws V layout (NEW): per 32-key tile t, 16KB contiguous in MFMA fragment
// order.  chunk16B index within tile = ((c>>5)*4 + (m>>3))*32 + (c&31);
// byte = chunk*16 + (m&7)*2.   Attention stages it with PURE LINEAR
// global_load_lds (uniform + lane*16) and reads with the proven r6 formula
// (identity verified: LDS slot s holds chunk s).
// ---------------------------------------------------------------------------

// ---------------------------------------------------------------------------
// Projection: [320x256] W @ [256x4096] x -> Qt[b][n][32], Kt[b][m][32],
// Vtile[b][t][frag16KB] (bf16).  grid 512 = 8 b x 64 n-blocks(64n = 2 tiles).
// 640 thr = 10 waves; wave w holds W A-fragments for o-tile w in REGISTERS
// (loaded once from L2).  xT 32n x 256c fragment-order, double-buffered,
// 2 barriers per half.
// ---------------------------------------------------------------------------
__global__ __launch_bounds__(640) void proj_kernel(
    const float* __restrict__ x,
    const float* __restrict__ wq, const float* __restrict__ bq,
    const float* __restrict__ wk, const float* __restrict__ bk,
    const float* __restrict__ wv, const float* __restrict__ bv,
    ushort_t* __restrict__ qtg, ushort_t* __restrict__ ktg,
    ushort_t* __restrict__ vtg)
{
  __shared__ ushort_t xT[2][32 * 256];   // 2 x 16KB, fragment order

  const int tid  = threadIdx.x;
  const int b    = blockIdx.x & 7;       // batch -> XCD pin
  const int nb   = blockIdx.x >> 3;      // 0..63
  const int tg0  = nb * 2;               // first of two global n-tiles
  const int lane = tid & 63;
  const int wid  = tid >> 6;             // 0..9
  const int l31  = lane & 31;
  const int half = lane >> 5;

  // ---- W A-fragments for this wave's o-tile, resident in registers ----
  const int o0 = wid * 32;
  const int grow = o0 + l31;
  const float* wrow = (o0 < 32) ? (wq + grow * 256)
                    : (o0 < 64) ? (wk + (grow - 32) * 256)
                                : (wv + (grow - 64) * 256);
  u32x4 af[16];
  #pragma unroll
  for (int kc = 0; kc < 16; ++kc) {
    f32x4v g0 = *(const f32x4v*)(wrow + kc * 16 + half * 8);
    f32x4v g1 = *(const f32x4v*)(wrow + kc * 16 + half * 8 + 4);
    af[kc].x = cvt_pk_bf16(g0.x, g0.y); af[kc].y = cvt_pk_bf16(g0.z, g0.w);
    af[kc].z = cvt_pk_bf16(g1.x, g1.y); af[kc].w = cvt_pk_bf16(g1.z, g1.w);
  }

  // ---- xT stage: 512 stager threads (wid<8): xn=tid&31, cg=tid>>5 ----
  #define STAGE_X(db, tg) do {                                                \
    if (wid < 8) {                                                            \
      const int xn = tid & 31;                                                \
      const int cg = tid >> 5;               /* 0..15 */                      \
      const float* xb = x + (size_t)b * 256 * 4096 + (tg) * 32 + xn;          \
      _Pragma("unroll")                                                       \
      for (int s = 0; s < 2; ++s) {                                           \
        const int c8 = cg * 2 + s;                                            \
        const int c0 = c8 * 8;                                                \
        float f0 = xb[(size_t)(c0+0)*4096], f1 = xb[(size_t)(c0+1)*4096];     \
        float f2 = xb[(size_t)(c0+2)*4096], f3 = xb[(size_t)(c0+3)*4096];     \
        float f4 = xb[(size_t)(c0+4)*4096], f5 = xb[(size_t)(c0+5)*4096];     \
        float f6 = xb[(size_t)(c0+6)*4096], f7 = xb[(size_t)(c0+7)*4096];     \
        u32x4 pk;                                                             \
        pk.x = cvt_pk_bf16(f0, f1); pk.y = cvt_pk_bf16(f2, f3);               \
        pk.z = cvt_pk_bf16(f4, f5); pk.w = cvt_pk_bf16(f6, f7);               \
        *(u32x4*)((char*)xT[db] + c8 * 512 + xn * 16) = pk;                   \
      }                                                                       \
    }                                                                         \
  } while (0)

  #define COMPUTE_STORE(db, tg) do {                                          \
    f32x16 acc = {};                                                          \
    _Pragma("unroll")                                                         \
    for (int kc = 0; kc < 16; ++kc) {                                         \
      u32x4 bf = *(const u32x4*)((char*)xT[db] + (kc*2 + half) * 512 + l31 * 16); \
      acc = mfma32(af[kc], bf, acc);                                          \
    }                                                                         \
    const int n = (tg) * 32 + l31;                                            \
    if (o0 < 64) {                                                            \
      ushort_t* dst = (o0 == 0) ? qtg : ktg;                                  \
      const float* bias = (o0 == 0) ? bq : bk;                                \
      const size_t rowbase = ((size_t)b * 4096 + n) * 32;                     \
      _Pragma("unroll")                                                       \
      for (int g = 0; g < 4; ++g) {                                           \
        const int ob = 8 * g + 4 * half;                                      \
        float v0 = acc[4*g+0] + bias[ob+0];                                   \
        float v1 = acc[4*g+1] + bias[ob+1];                                   \
        float v2 = acc[4*g+2] + bias[ob+2];                                   \
        float v3 = acc[4*g+3] + bias[ob+3];                                   \
        u32x2 pk2; pk2.x = cvt_pk_bf16(v0, v1); pk2.y = cvt_pk_bf16(v2, v3);  \
        *(u32x2*)(dst + rowbase + ob) = pk2;                                  \
      }                                                                       \
    } else {                                                                  \
      const int cbase = o0 - 64;                                              \
      char* tb = (char*)vtg + (size_t)(b * 128 + (tg)) * 16384;               \
      _Pragma("unroll")                                                       \
      for (int r = 0; r < 16; ++r) {                                          \
        const int c = cbase + (r & 3) + 8 * (r >> 2) + 4 * half;              \
        const int m = l31;                                                    \
        float v = acc[r] + bv[c];                                             \
        *(ushort_t*)(tb + (((c >> 5) * 4 + (m >> 3)) * 32 + (c & 31)) * 16    \
                        + (m & 7) * 2) = (ushort_t)cvt_pk_bf16(v, v);         \
      }                                                                       \
    }                                                                         \
  } while (0)

  STAGE_X(0, tg0);
  __syncthreads();
  STAGE_X(1, tg0 + 1);      // issue early; hides under compute of tile 0
  COMPUTE_STORE(0, tg0);
  __syncthreads();
  COMPUTE_STORE(1, tg0 + 1);
}

// online-softmax + P-pack for one 32q S-tile (proven round-1 construction)
#define SOFTMAX_PACK(S, MR, LR, OB, PB0, PB1) do {                            \
  float y0 = fmaxf(fmaxf(S[0],  S[1]),  fmaxf(S[2],  S[3]));                  \
  float y1 = fmaxf(fmaxf(S[4],  S[5]),  fmaxf(S[6],  S[7]));                  \
  float y2 = fmaxf(fmaxf(S[8],  S[9]),  fmaxf(S[10], S[11]));                 \
  float y3 = fmaxf(fmaxf(S[12], S[13]), fmaxf(S[14], S[15]));                 \
  const float vmx  = fmaxf(fmaxf(y0, y1), fmaxf(y2, y3));                     \
  const float pmax = fmaxf(vmx, __shfl_xor(vmx, 32, 64));                     \
  if (__any(pmax > (MR) + 8.0f)) {                                            \
    const float mnew = fmaxf((MR), pmax);                                     \
    const float sc   = fast_exp2(((MR) - mnew) * L2E);                        \
    (LR) *= sc;                                                               \
    _Pragma("unroll")                                                         \
    for (int ct_ = 0; ct_ < 4; ++ct_) {                                       \
      _Pragma("unroll")                                                       \
      for (int r_ = 0; r_ < 16; ++r_) oacc[(OB) + ct_][r_] *= sc;             \
    }                                                                         \
    (MR) = mnew;                                                              \
  }                                                                           \
  const float ml2 = (MR) * L2E;                                               \
  float p_[16];                                                               \
  _Pragma("unroll")                                                           \
  for (int r_ = 0; r_ < 16; ++r_) p_[r_] = fast_exp2(fmaf(S[r_], L2E, -ml2)); \
  const float ps = (((p_[0]+p_[1])+(p_[2]+p_[3])) + ((p_[4]+p_[5])+(p_[6]+p_[7]))) \
                 + (((p_[8]+p_[9])+(p_[10]+p_[11])) + ((p_[12]+p_[13])+(p_[14]+p_[15]))); \
  (LR) += ps + __shfl_xor(ps, 32, 64);                                        \
  const unsigned wd0 = cvt_pk_bf16(p_[0],  p_[1]),  wd1 = cvt_pk_bf16(p_[2],  p_[3]);  \
  const unsigned wd2 = cvt_pk_bf16(p_[4],  p_[5]),  wd3 = cvt_pk_bf16(p_[6],  p_[7]);  \
  const unsigned wd4 = cvt_pk_bf16(p_[8],  p_[9]),  wd5 = cvt_pk_bf16(p_[10], p_[11]); \
  const unsigned wd6 = cvt_pk_bf16(p_[12], p_[13]), wd7 = cvt_pk_bf16(p_[14], p_[15]); \
  const unsigned pw0 = __shfl_xor((int)wd0, 32, 64), pw1 = __shfl_xor((int)wd1, 32, 64); \
  const unsigned pw2 = __shfl_xor((int)wd2, 32, 64), pw3 = __shfl_xor((int)wd3, 32, 64); \
  const unsigned pw4 = __shfl_xor((int)wd4, 32, 64), pw5 = __shfl_xor((int)wd5, 32, 64); \
  const unsigned pw6 = __shfl_xor((int)wd6, 32, 64), pw7 = __shfl_xor((int)wd7, 32, 64); \
  PB0.x = half ? pw2 : wd0;  PB0.y = half ? pw3 : wd1;                        \
  PB0.z = half ? wd2 : pw0;  PB0.w = half ? wd3 : pw1;                        \
  PB1.x = half ? pw6 : wd4;  PB1.y = half ? pw7 : wd5;                        \
  PB1.z = half ? wd6 : pw4;  PB1.w = half ? wd7 : pw5;                        \
} while (0)

// ---------------------------------------------------------------------------
// Flash attention, barrier-free loop + private per-wave LDS V double-buffer.
// grid 512 = 8 b x 64 q-tiles(64q); 256 thr = 4 waves = 2 cs(128ch) x 2 ks.
// V staging is now PURE LINEAR (fragment-order ws tiles): 8 x 1KB contiguous
// global_load_lds per tile.  Reads unchanged from proven r6 kernel.
// ---------------------------------------------------------------------------
__global__ __launch_bounds__(256, 2) void attn_kernel(
    const ushort_t* __restrict__ qtg, const ushort_t* __restrict__ ktg,
    const ushort_t* __restrict__ vtg, const float* __restrict__ x,
    const float* __restrict__ gamma, float* __restrict__ out)
{
  __shared__ __align__(16) char smem[69632];  // [0,64K): 4x16KB wave V dbufs
                                              //          (aliased by merge obuf)
                                              // [64K,68K): m/l exchange

  const int tid  = threadIdx.x;
  const int lane = tid & 63;
  const int wid  = tid >> 6;           // 0..3
  const int l31  = lane & 31;
  const int half = lane >> 5;
  const int ks   = wid & 1;            // tile parity
  const int cs   = wid >> 1;           // channel half
  const int b    = blockIdx.x & 7;     // batch -> XCD pin (V L2-resident)
  const int qt   = blockIdx.x >> 3;    // 0..63
  const int qbase = qt * 64;

  const ushort_t* ktb = ktg + (size_t)b * 4096 * 32;
  char* vbuf = smem + wid * 16384;     // private: 2 x 8KB

  // persistent Q B-fragments (2 q-subtiles x 2 o-chunks)
  const ushort_t* qr0 = qtg + ((size_t)b * 4096 + qbase + l31) * 32;
  const ushort_t* qr1 = qr0 + 32 * 32;
  const u32x4 qf00 = *(const u32x4*)(qr0 + half * 8);
  const u32x4 qf01 = *(const u32x4*)(qr0 + 16 + half * 8);
  const u32x4 qf10 = *(const u32x4*)(qr1 + half * 8);
  const u32x4 qf11 = *(const u32x4*)(qr1 + 16 + half * 8);

  // stage V tile t -> private buffer db: 8 linear 1KB chunks
  #define STAGE_V(db, t_) do {                                                \
    const char* tb = (const char*)vtg + (size_t)(b * 128 + (t_)) * 16384      \
                     + cs * 8192 + lane * 16;                                 \
    _Pragma("unroll")                                                         \
    for (int j = 0; j < 8; ++j) {                                             \
      __builtin_amdgcn_global_load_lds(                                       \
          (const __attribute__((address_space(1))) void*)(tb + j * 1024),     \
          (__attribute__((address_space(3))) void*)(vbuf + (db)*8192 + j*1024), \
          16, 0, 0);                                                          \
    }                                                                         \
  } while (0)

  // prologue: K(t0) regs + V(t0) -> buf0
  u32x4 kf0 = *(const u32x4*)(ktb + (size_t)(ks * 32 + l31) * 32 + half * 8);
  u32x4 kf1 = *(const u32x4*)(ktb + (size_t)(ks * 32 + l31) * 32 + 16 + half * 8);
  STAGE_V(0, ks);

  float mr0 = -3.0e38f, mr1 = -3.0e38f, lr0 = 0.0f, lr1 = 0.0f;
  f32x16 oacc[8] = {};                 // [qt2*4 + ct]

  for (int i = 0; i < 64; ++i) {
    const int t  = 2 * i + ks;
    const int tn = (i < 63) ? (t + 2) : t;   // clamped -> uniform 10 issues

    // K prefetch (2 vmem), then V stage for next tile (8 vmem)
    const ushort_t* kr = ktb + (size_t)(tn * 32 + l31) * 32;
    u32x4 kn0 = *(const u32x4*)(kr + half * 8);
    u32x4 kn1 = *(const u32x4*)(kr + 16 + half * 8);
    STAGE_V((i + 1) & 1, tn);

    // wait: everything older than this iter's 10 issues (V(t), K(t) done)
    asm volatile("s_waitcnt vmcnt(10)" ::: "memory");
    __builtin_amdgcn_sched_barrier(0);

    // V fragments: lane-linear conflict-free ds_read_b128
    const char* vb = vbuf + (i & 1) * 8192;
    u32x4 vf[4][2];
    #pragma unroll
    for (int ct = 0; ct < 4; ++ct)
      #pragma unroll
      for (int mh = 0; mh < 2; ++mh)
        vf[ct][mh] = *(const u32x4*)(vb + (ct*4 + mh*2 + half) * 512 + l31 * 16);

    // S^T = K . Q^T for both q-subtiles
    f32x16 s0 = {}, s1 = {};
    __builtin_amdgcn_s_setprio(1);
    s0 = mfma32(kf0, qf00, s0);  s0 = mfma32(kf1, qf01, s0);
    s1 = mfma32(kf0, qf10, s1);  s1 = mfma32(kf1, qf11, s1);
    __builtin_amdgcn_s_setprio(0);

    // qt2 = 0
    {
      u32x4 pb0, pb1;
      SOFTMAX_PACK(s0, mr0, lr0, 0, pb0, pb1);
      __builtin_amdgcn_s_setprio(1);
      #pragma unroll
      for (int ct = 0; ct < 4; ++ct) {
        oacc[ct] = mfma32(vf[ct][0], pb0, oacc[ct]);
        oacc[ct] = mfma32(vf[ct][1], pb1, oacc[ct]);
      }
      __builtin_amdgcn_s_setprio(0);
    }
    // qt2 = 1
    {
      u32x4 pb0, pb1;
      SOFTMAX_PACK(s1, mr1, lr1, 4, pb0, pb1);
      __builtin_amdgcn_s_setprio(1);
      #pragma unroll
      for (int ct = 0; ct < 4; ++ct) {
        oacc[4 + ct] = mfma32(vf[ct][0], pb0, oacc[4 + ct]);
        oacc[4 + ct] = mfma32(vf[ct][1], pb1, oacc[4 + ct]);
      }
      __builtin_amdgcn_s_setprio(0);
    }

    kf0 = kn0; kf1 = kn1;
  }

  // drain the final (redundant) stage before aliasing the buffers
  asm volatile("s_waitcnt vmcnt(0)" ::: "memory");

  // ---- flash merge across ks pairs (partner wave = wid ^ 1) ----
  float* mls = (float*)(smem + 65536);       // [2][8][64]
  mls[(0*8 + wid*2 + 0)*64 + lane] = mr0;
  mls[(0*8 + wid*2 + 1)*64 + lane] = mr1;
  mls[(1*8 + wid*2 + 0)*64 + lane] = lr0;
  mls[(1*8 + wid*2 + 1)*64 + lane] = lr1;
  __syncthreads();
  const int pw = (wid ^ 1) * 2;
  const float mO0 = mls[(0*8 + pw + 0)*64 + lane], lO0 = mls[(1*8 + pw + 0)*64 + lane];
  const float mO1 = mls[(0*8 + pw + 1)*64 + lane], lO1 = mls[(1*8 + pw + 1)*64 + lane];
  const float mS0 = fmaxf(mr0, mO0), mS1 = fmaxf(mr1, mO1);
  const float aS0 = fast_exp2((mr0 - mS0) * L2E), aO0 = fast_exp2((mO0 - mS0) * L2E);
  const float aS1 = fast_exp2((mr1 - mS1) * L2E), aO1 = fast_exp2((mO1 - mS1) * L2E);
  const float li0 = 1.0f / (aS0 * lr0 + aO0 * lO0);
  const float li1 = 1.0f / (aS1 * lr1 + aO1 * lO1);

  float (*obuf)[16][64] = (float (*)[16][64])smem;   // 16 slots, aliases vbufs

  if (ks == 1) {                       // partner writes scaled O
    #pragma unroll
    for (int qt2 = 0; qt2 < 2; ++qt2) {
      const float aS = qt2 ? aS1 : aS0;
      #pragma unroll
      for (int ct = 0; ct < 4; ++ct) {
        const int slot = cs * 8 + qt2 * 4 + ct;
        #pragma unroll
        for (int r = 0; r < 16; ++r)
          obuf[slot][r][lane] = aS * oacc[qt2 * 4 + ct][r];
      }
    }
  }
  __syncthreads();
  if (ks == 0) {                       // combine + store
    const float g = gamma[0];
    const size_t base = (size_t)b * 256 * 4096;
    #pragma unroll
    for (int qt2 = 0; qt2 < 2; ++qt2) {
      const float aS = qt2 ? aS1 : aS0;
      const float li = qt2 ? li1 : li0;
      const size_t n = qbase + qt2 * 32 + l31;
      #pragma unroll
      for (int ct = 0; ct < 4; ++ct) {
        const int slot = cs * 8 + qt2 * 4 + ct;
        #pragma unroll
        for (int r = 0; r < 16; ++r) {
          const float oS = aS * oacc[qt2 * 4 + ct][r] + obuf[slot][r][lane];
          const int c = cs * 128 + ct * 32 + (r & 3) + 8 * (r >> 2) + 4 * half;
          const size_t off = base + (size_t)c * 4096 + n;
          out[off] = x[off] + g * (oS * li);
        }
      }
    }
  }
}

extern "C" void kernel_launch(void* const* d_in, const int* in_sizes, int n_in,
                              void* d_out, int out_size, void* d_ws, size_t ws_size,
                              hipStream_t stream) {
  (void)in_sizes; (void)n_in; (void)out_size; (void)ws_size;
  const float* x     = (const float*)d_in[0];
  const float* wq    = (const float*)d_in[1];
  const float* bq    = (const float*)d_in[2];
  const float* wk    = (const float*)d_in[3];
  const float* bk    = (const float*)d_in[4];
  const float* wv    = (const float*)d_in[5];
  const float* bv    = (const float*)d_in[6];
  const float* gamma = (const float*)d_in[7];
  float* out = (float*)d_out;

  ushort_t* ws  = (ushort_t*)d_ws;
  ushort_t* qtw = ws;                              // [8][4096][32] bf16
  ushort_t* ktw = ws + (size_t)8*4096*32;          // [8][4096][32] bf16
  ushort_t* vww = ws + (size_t)2*8*4096*32;        // [8][128 tiles][16KB frag]

  proj_kernel<<<512, 640, 0, stream>>>(x, wq, bq, wk, bk, wv, bv, qtw, ktw, vww);
  attn_kernel<<<512, 256, 0, stream>>>(qtw, ktw, vww, x, gamma, out);
}